// Round 11
// baseline (298.443 us; speedup 1.0000x reference)
//
#include <hip/hip_runtime.h>

// Quantizer via bf16x3-split MFMA GEMM + exact-fp32 recheck of near-ties.
//   x: [16,64,32,32] fp32, embed: [64,8192] fp32
//   out[row][c] = embedT[argmax_j (f_row.e_j - ||e_j||^2/2)][c]
//
// R11: reduce_rows fused into qdist via last-chunk-finisher (threadfence +
// done-counter per rowblock): 5 kernels -> 4. R10 showed nt=4 vs nt=8 makes
// no difference (limiter = MFMA floor + epilogue VALU + barrier drain), so
// the tail (~85us across extra launches) is the target.

typedef __attribute__((ext_vector_type(8))) __bf16 bf16x8;
typedef __attribute__((ext_vector_type(4))) float f32x4;
typedef unsigned int u32;
typedef unsigned long long u64;

union frag_cast { f32x4 f; bf16x8 b; };
__device__ __forceinline__ bf16x8 as_bf16x8(f32x4 v) { frag_cast u; u.f = v; return u.b; }

#define N_ROWS  16384
#define E_DIM   64
#define N_EMBED 8192
#define NCHUNK  16
#define COLS_PER_BLOCK (N_EMBED / NCHUNK)   // 512
#define N_ST (COLS_PER_BLOCK / 64)          // 8 stages of 64 codes
#define ROWS_PER_BLOCK 256                  // 4 waves x 64 pixels; 1 row/thread in finisher
#define N_ROWBLK (N_ROWS / ROWS_PER_BLOCK)  // 64
#define MARGIN_THR 2e-3f

// ---- workspace byte offsets (~11.8 MB total)
#define WS_AH   0u              // pixel hi  [16384][64] bf16 (2 MB)
#define WS_AL   (2u << 20)      // pixel lo  (2 MB)
#define WS_B    (4u << 20)      // codes: 128 groups x [hi 64x128B | lo 64x128B] (2 MB)
#define WS_ET   (6u << 20)      // embedT fp32 [8192][64] (2 MB)
#define WS_BIAS (8u << 20)      // -||e_j||^2/2 (32 KB)
#define WS_PB1  (WS_BIAS + (64u << 10))     // 1 MB
#define WS_PI1  (WS_PB1 + (1u << 20))       // 1 MB
#define WS_PB2  (WS_PI1 + (1u << 20))       // 1 MB
#define WS_FIDX (WS_PB2 + (1u << 20))       // 64 KB
#define WS_FLAG (WS_FIDX + (64u << 10))     // 64 KB
#define WS_CNT  (WS_FLAG + (64u << 10))     // 4 KB
#define WS_FKEY (WS_CNT + (4u << 10))       // 128 KB u64 keys
#define WS_DONE (WS_FKEY + (128u << 10))    // 64 ints (rowblock done counters)

__device__ __forceinline__ u32 f32_key(float s) {
    u32 u = __float_as_uint(s);
    return (u & 0x80000000u) ? ~u : (u | 0x80000000u);
}

__device__ __forceinline__ void async16(const void* g, void* l) {
    __builtin_amdgcn_global_load_lds(
        (const __attribute__((address_space(1))) void*)g,
        (__attribute__((address_space(3))) void*)l, 16, 0, 0);
}

// ---- K1: prep. Blocks 0..255: split x -> A_hi/A_lo [row][64] bf16.
//          Blocks 256..383: embedT fp32, bias, swizzled code groups; blk 256 zeroes counters.
__global__ __launch_bounds__(256) void prep(
        const float* __restrict__ x, const float* __restrict__ embed, char* ws) {
    __shared__ float tile[64][65];
    __bf16* Ah = (__bf16*)(ws + WS_AH);
    __bf16* Al = (__bf16*)(ws + WS_AL);
    float*  eT = (float*)(ws + WS_ET);
    float*  bias = (float*)(ws + WS_BIAS);
    const int t = threadIdx.x;
    const int blk = blockIdx.x;

    if (blk < 256) {
        const int b = blk >> 4, p0 = (blk & 15) * 64;
        {
            const int c = t >> 2, seg = (t & 3) * 16;
            const float* src = x + b * 65536 + c * 1024 + p0 + seg;
#pragma unroll
            for (int i = 0; i < 16; ++i) tile[c][seg + i] = src[i];
        }
        __syncthreads();
        const int p = t >> 2, cq = (t & 3) * 16;
        const long row = b * 1024 + p0 + p;
        bf16x8 vh0, vh1, vl0, vl1;
#pragma unroll
        for (int i = 0; i < 16; ++i) {
            float f = tile[cq + i][p];
            __bf16 h = (__bf16)f;
            __bf16 l = (__bf16)(f - (float)h);
            if (i < 8) { vh0[i] = h; vl0[i] = l; }
            else       { vh1[i - 8] = h; vl1[i - 8] = l; }
        }
        *(bf16x8*)(Ah + row * 64 + cq) = vh0;
        *(bf16x8*)(Ah + row * 64 + cq + 8) = vh1;
        *(bf16x8*)(Al + row * 64 + cq) = vl0;
        *(bf16x8*)(Al + row * 64 + cq + 8) = vl1;
    } else {
        if (blk == 256) {
            if (t == 0) *(int*)(ws + WS_CNT) = 0;
            if (t < N_ROWBLK) ((int*)(ws + WS_DONE))[t] = 0;
        }
        const int g = blk - 256;             // 64-code group
        const int jbase = g * 64;
        char* Bg = ws + WS_B + (size_t)g * 16384;
        {
            const int c = t >> 2, seg = (t & 3) * 16;
            const float* src = embed + c * N_EMBED + jbase + seg;
#pragma unroll
            for (int i = 0; i < 16; ++i) tile[c][seg + i] = src[i];
        }
        __syncthreads();
        if (t < 64) {
            float s = 0.f;
#pragma unroll
            for (int c = 0; c < 64; ++c) { float v = tile[c][t]; s = fmaf(v, v, s); }
            bias[jbase + t] = -0.5f * s;
        }
        const int jl = t >> 2, cq = (t & 3) * 16;   // channels cq..cq+15
        bf16x8 vh0, vh1, vl0, vl1;
#pragma unroll
        for (int i = 0; i < 16; ++i) {
            float f = tile[cq + i][jl];
            eT[(long)(jbase + jl) * 64 + cq + i] = f;
            __bf16 h = (__bf16)f;
            __bf16 l = (__bf16)(f - (float)h);
            if (i < 8) { vh0[i] = h; vl0[i] = l; }
            else       { vh1[i - 8] = h; vl1[i - 8] = l; }
        }
        // granule-XOR swizzle: logical granule k (8 bf16) of code jl stored at
        // position k ^ (jl & 7). Keeps staging contiguous, LDS reads conflict-free.
        const int k0 = (cq >> 3), sw = jl & 7;
        __bf16* hi = (__bf16*)Bg + jl * 64;
        __bf16* lo = (__bf16*)(Bg + 8192) + jl * 64;
        *(bf16x8*)(hi + ((k0 ^ sw) * 8))       = vh0;
        *(bf16x8*)(hi + (((k0 + 1) ^ sw) * 8)) = vh1;
        *(bf16x8*)(lo + ((k0 ^ sw) * 8))       = vl0;
        *(bf16x8*)(lo + (((k0 + 1) ^ sw) * 8)) = vl1;
    }
}

// ---- K2: MFMA GEMM + running (quad-max top-2) argmax + fused row-reduce.
// grid 1024 blocks (64 rowblk x 16 chunks), 256 thr, 4 blocks/CU.
__global__ __launch_bounds__(256, 4) void qdist(const float* __restrict__ x,
                                                const char* __restrict__ ws_c,
                                                char* __restrict__ ws) {
    __shared__ __align__(16) char smem[2][16384];
    __shared__ int ticket_s;
    const __bf16* Ah = (const __bf16*)(ws_c + WS_AH);
    const __bf16* Al = (const __bf16*)(ws_c + WS_AL);
    const char* Bws = ws_c + WS_B;
    const float* biasg = (const float*)(ws_c + WS_BIAS);
    float* pb1 = (float*)(ws + WS_PB1);
    int*   pi1 = (int*)(ws + WS_PI1);
    float* pb2 = (float*)(ws + WS_PB2);

    const int t = threadIdx.x;
    const int wv = t >> 6, lane = t & 63, ln = lane & 15, q = lane >> 4;
    const int rb = blockIdx.x >> 4, chunk = blockIdx.x & 15;
    const int row0 = rb * ROWS_PER_BLOCK;
    const int col0 = chunk * COLS_PER_BLOCK;
    const int g0 = col0 >> 6;               // first 64-code group of this chunk

    // resident pixel fragments (B-operand): 4 pixel-tiles x 2 K-halves x {hi,lo}
    f32x4 pfh[4][2], pfl[4][2];
#pragma unroll
    for (int nt = 0; nt < 4; ++nt) {
        long row = row0 + wv * 64 + nt * 16 + ln;
        long base = row * 64 + q * 8;
        pfh[nt][0] = *(const f32x4*)(Ah + base);
        pfh[nt][1] = *(const f32x4*)(Ah + base + 32);
        pfl[nt][0] = *(const f32x4*)(Al + base);
        pfl[nt][1] = *(const f32x4*)(Al + base + 32);
    }
    asm volatile("" :
        "+v"(pfh[0][0]), "+v"(pfh[0][1]), "+v"(pfh[1][0]), "+v"(pfh[1][1]),
        "+v"(pfh[2][0]), "+v"(pfh[2][1]), "+v"(pfh[3][0]), "+v"(pfh[3][1]),
        "+v"(pfl[0][0]), "+v"(pfl[0][1]), "+v"(pfl[1][0]), "+v"(pfl[1][1]),
        "+v"(pfl[2][0]), "+v"(pfl[2][1]), "+v"(pfl[3][0]), "+v"(pfl[3][1]));

    float b1[4], b2[4]; int iq[4];
#pragma unroll
    for (int k = 0; k < 4; ++k) { b1[k] = -3.4e38f; b2[k] = -3.4e38f; iq[k] = 0; }

    // swizzled fragment read offsets: code cl=ct*16+ln; hi-K0 granule q^(ln&7)
    const int s7 = ln & 7;
    const int rdbase = ln * 128 + ((q ^ s7) << 4);

    auto issue = [&](int st) {
        const char* src = Bws + (size_t)(g0 + st) * 16384;
        char* dst = smem[st & 1];
#pragma unroll
        for (int s = 0; s < 4; ++s)
            async16(src + s * 4096 + wv * 1024 + lane * 16,
                    dst + s * 4096 + wv * 1024);
    };

    issue(0);
    for (int st = 0; st < N_ST; ++st) {
        __syncthreads();                 // own staging drained (vmcnt0 before barrier);
        if (st + 1 < N_ST) issue(st + 1);// all waves done reading buf[(st+1)&1]
        const char* buf = smem[st & 1];
#pragma unroll
        for (int ct = 0; ct < 4; ++ct) {
            const int boff = ct * 2048 + rdbase;
            bf16x8 ah0 = *(const bf16x8*)(buf + boff);
            bf16x8 ah1 = *(const bf16x8*)(buf + (boff ^ 64));
            bf16x8 al0 = *(const bf16x8*)(buf + 8192 + boff);
            bf16x8 al1 = *(const bf16x8*)(buf + 8192 + (boff ^ 64));
            const int cbase = col0 + st * 64 + ct * 16;
            f32x4 bv = *(const f32x4*)(biasg + cbase + q * 4);  // bias for 4 codes
            const int jq = cbase + q * 4;
#pragma unroll
            for (int nt = 0; nt < 4; ++nt) {
                f32x4 acc = __builtin_amdgcn_mfma_f32_16x16x32_bf16(al0, as_bf16x8(pfh[nt][0]), bv, 0, 0, 0);
                acc = __builtin_amdgcn_mfma_f32_16x16x32_bf16(al1, as_bf16x8(pfh[nt][1]), acc, 0, 0, 0);
                acc = __builtin_amdgcn_mfma_f32_16x16x32_bf16(ah0, as_bf16x8(pfl[nt][0]), acc, 0, 0, 0);
                acc = __builtin_amdgcn_mfma_f32_16x16x32_bf16(ah1, as_bf16x8(pfl[nt][1]), acc, 0, 0, 0);
                acc = __builtin_amdgcn_mfma_f32_16x16x32_bf16(ah0, as_bf16x8(pfh[nt][0]), acc, 0, 0, 0);
                acc = __builtin_amdgcn_mfma_f32_16x16x32_bf16(ah1, as_bf16x8(pfh[nt][1]), acc, 0, 0, 0);
                // quad max (4 codes of one pixel)
                float mx = fmaxf(fmaxf(acc[0], acc[1]), fmaxf(acc[2], acc[3]));
                b2[nt] = fmaxf(b2[nt], fminf(b1[nt], mx));
                bool gt = mx > b1[nt];
                b1[nt] = fmaxf(b1[nt], mx);
                iq[nt] = gt ? jq : iq[nt];
            }
        }
    }

    // merge across the 4 quads (same pixel lives in lanes ln, ln+16, ln+32, ln+48)
#pragma unroll
    for (int m = 16; m < 64; m <<= 1) {
#pragma unroll
        for (int nt = 0; nt < 4; ++nt) {
            float o1 = __shfl_xor(b1[nt], m);
            int   oi = __shfl_xor(iq[nt], m);
            float o2 = __shfl_xor(b2[nt], m);
            b2[nt] = fmaxf(fmaxf(fminf(b1[nt], o1), o2), b2[nt]);
            bool take = (o1 > b1[nt]) || (o1 == b1[nt] && oi < iq[nt]);
            if (take) { b1[nt] = o1; iq[nt] = oi; }
        }
    }
    if (q == 0) {
#pragma unroll
        for (int nt = 0; nt < 4; ++nt) {
            int pixel = row0 + wv * 64 + nt * 16 + ln;
            int o = chunk * N_ROWS + pixel;
            pb1[o] = b1[nt];
            pi1[o] = iq[nt];
            pb2[o] = b2[nt];
        }
    }

    // ---- fused row-reduce: last chunk-block of this rowblock finishes the rows
    __threadfence();                 // release this block's partials (device scope)
    __syncthreads();                 // all threads fenced before the ticket
    if (t == 0) ticket_s = atomicAdd((int*)(ws + WS_DONE) + rb, 1);
    __syncthreads();
    if (ticket_s == NCHUNK - 1) {
        __threadfence();             // acquire: see all chunks' partials
        const float* eT = (const float*)(ws_c + WS_ET);
        int* fidx = (int*)(ws + WS_FIDX);
        int* flags = (int*)(ws + WS_FLAG);
        int* cnt = (int*)(ws + WS_CNT);
        u64* fkey = (u64*)(ws + WS_FKEY);
        const int row = row0 + t;    // one row per thread

        float rb1 = pb1[row]; int riq = pi1[row]; float rb2 = pb2[row];
#pragma unroll
        for (int ch = 1; ch < NCHUNK; ++ch) {
            float o1 = pb1[ch * N_ROWS + row];
            int   oi = pi1[ch * N_ROWS + row];
            float o2 = pb2[ch * N_ROWS + row];
            rb2 = fmaxf(fmaxf(fminf(rb1, o1), o2), rb2);
            if (o1 > rb1 || (o1 == rb1 && oi < riq)) { rb1 = o1; riq = oi; }
        }

        if (rb1 - rb2 < MARGIN_THR) {
            fidx[row] = -1;                   // marker: decode from fkey
            fkey[row] = 0ull;                 // any finite score key > 0
            flags[atomicAdd(cnt, 1)] = row;
        } else {
            // exact fp32 argmax within the winning quad (codes riq..riq+3)
            float xr[64];
            const float* xb = x + (row >> 10) * 65536 + (row & 1023);
#pragma unroll
            for (int c = 0; c < 64; ++c) xr[c] = xb[c * 1024];
            float best = -3.4e38f; int bi = riq;
#pragma unroll
            for (int cc = 0; cc < 4; ++cc) {
                const int j = riq + cc;
                const float* e = eT + j * 64;
                float s = biasg[j];
#pragma unroll
                for (int c = 0; c < 64; ++c) s = fmaf(xr[c], e[c], s);
                if (s > best) { best = s; bi = j; }   // strict >, ascending j
            }
            fidx[row] = bi;
        }
    }
}

// ---- K3: exact fp32 rescan of flagged rows, 32 blocks/row x 256 codes/block
__global__ __launch_bounds__(256) void recheck(const float* __restrict__ x, char* ws) {
    __shared__ float fl[64];
    __shared__ u64 red[256];
    const float* eT = (const float*)(ws + WS_ET);
    const float* bias = (const float*)(ws + WS_BIAS);
    const int* flags = (const int*)(ws + WS_FLAG);
    const int n = *(const int*)(ws + WS_CNT);
    u64* fkey = (u64*)(ws + WS_FKEY);
    const int t = threadIdx.x;
    const int seg = blockIdx.x & 31;
    const int rstep = gridDim.x >> 5;
    const int j = seg * 256 + t;             // this thread's code

    for (int rowi = blockIdx.x >> 5; rowi < n; rowi += rstep) {
        const int row = flags[rowi];
        __syncthreads();
        if (t < 64) fl[t] = x[(row >> 10) * 65536 + t * 1024 + (row & 1023)];
        __syncthreads();
        float xr[64];
#pragma unroll
        for (int c = 0; c < 64; ++c) xr[c] = fl[c];

        const f32x4* e = (const f32x4*)(eT + (size_t)j * 64);
        f32x4 a0 = {0.f, 0.f, 0.f, 0.f}, a1 = a0, a2 = a0, a3 = a0;
#pragma unroll
        for (int v = 0; v < 4; ++v) {
            f32x4 e0 = e[v * 4 + 0], e1 = e[v * 4 + 1];
            f32x4 e2 = e[v * 4 + 2], e3 = e[v * 4 + 3];
#pragma unroll
            for (int k = 0; k < 4; ++k) {
                a0[k] = fmaf(xr[v * 16 + k],      e0[k], a0[k]);
                a1[k] = fmaf(xr[v * 16 + 4 + k],  e1[k], a1[k]);
                a2[k] = fmaf(xr[v * 16 + 8 + k],  e2[k], a2[k]);
                a3[k] = fmaf(xr[v * 16 + 12 + k], e3[k], a3[k]);
            }
        }
        f32x4 a01 = a0 + a1, a23 = a2 + a3;
        f32x4 as = a01 + a23;
        float s = bias[j] + ((as[0] + as[1]) + (as[2] + as[3]));

        red[t] = ((u64)f32_key(s) << 32) | (u32)(~(u32)j);
        __syncthreads();
        for (int off = 128; off; off >>= 1) {
            if (t < off) { u64 o = red[t + off]; if (o > red[t]) red[t] = o; }
            __syncthreads();
        }
        if (t == 0) atomicMax(&fkey[row], red[0]);
        __syncthreads();
    }
}

// ---- K4: gather winning codes; flagged rows decode from fkey
__global__ __launch_bounds__(256) void gather_out(const char* __restrict__ ws,
                                                  float* __restrict__ out) {
    const int* fidx = (const int*)(ws + WS_FIDX);
    const u64* fkey = (const u64*)(ws + WS_FKEY);
    const float* eT = (const float*)(ws + WS_ET);
    int g = blockIdx.x * 256 + threadIdx.x;
    int row = g >> 6, c = g & 63;
    int idx = fidx[row];
    if (idx < 0) idx = (int)(~(u32)(fkey[row] & 0xffffffffull));
    out[g] = eT[idx * 64 + c];
}

extern "C" void kernel_launch(void* const* d_in, const int* in_sizes, int n_in,
                              void* d_out, int out_size, void* d_ws, size_t ws_size,
                              hipStream_t stream) {
    const float* x     = (const float*)d_in[0];
    const float* embed = (const float*)d_in[1];
    float* out = (float*)d_out;
    char* ws = (char*)d_ws;

    prep<<<384, 256, 0, stream>>>(x, embed, ws);
    qdist<<<N_ROWBLK * NCHUNK, 256, 0, stream>>>(x, ws, ws);
    recheck<<<2048, 256, 0, stream>>>(x, ws);
    gather_out<<<(N_ROWS * 64) / 256, 256, 0, stream>>>(ws, out);
}

// Round 12
// 262.765 us; speedup vs baseline: 1.1358x; 1.1358x over previous
//
#include <hip/hip_runtime.h>

// Quantizer via bf16x3-split MFMA GEMM + exact-fp32 recheck of near-ties.
//   x: [16,64,32,32] fp32, embed: [64,8192] fp32
//   out[row][c] = embedT[argmax_j (f_row.e_j - ||e_j||^2/2)][c]
//
// R12: 3 kernels. prep writes fp32 xT (pixel-major) + swizzled bf16 codes;
// qdist = R9's clean 50us version (nt=8, launch_bounds(256,2), no spills)
// with the hi/lo bf16 split done in-register from xT; finish merges chunk
// partials, exact quad-pick, cooperative in-block rescan of near-ties, and
// the output gather -- all in one launch (was reduce_rows+recheck+gather).

typedef __attribute__((ext_vector_type(8))) __bf16 bf16x8;
typedef __attribute__((ext_vector_type(4))) float f32x4;
typedef unsigned int u32;
typedef unsigned long long u64;

union frag_cast { f32x4 f; bf16x8 b; };
__device__ __forceinline__ bf16x8 as_bf16x8(f32x4 v) { frag_cast u; u.f = v; return u.b; }

// split 8 fp32 (two f32x4) into bf16 hi / bf16 lo fragments (RNE casts,
// identical numerics to the old prep-side split)
__device__ __forceinline__ void split8(f32x4 a, f32x4 b, f32x4& ho, f32x4& lo_) {
    frag_cast h, l;
#pragma unroll
    for (int i = 0; i < 4; ++i) {
        __bf16 ha = (__bf16)a[i];
        __bf16 hb = (__bf16)b[i];
        h.b[i]     = ha;
        h.b[i + 4] = hb;
        l.b[i]     = (__bf16)(a[i] - (float)ha);
        l.b[i + 4] = (__bf16)(b[i] - (float)hb);
    }
    ho = h.f; lo_ = l.f;
}

#define N_ROWS  16384
#define E_DIM   64
#define N_EMBED 8192
#define NCHUNK  16
#define COLS_PER_BLOCK (N_EMBED / NCHUNK)   // 512
#define N_ST (COLS_PER_BLOCK / 64)          // 8 stages of 64 codes
#define ROWS_PER_BLOCK 512                  // 4 waves x 128 pixels
#define N_ROWBLK (N_ROWS / ROWS_PER_BLOCK)  // 32
#define MARGIN_THR 2e-3f

// ---- workspace byte offsets (~11.1 MB total, under the ~11.9 MB proven OK)
#define WS_XT   0u                          // pixels fp32 [16384][64] (4 MB)
#define WS_B    (4u << 20)                  // codes: 128 groups x [hi 8KB | lo 8KB] (2 MB)
#define WS_ET   (6u << 20)                  // embedT fp32 [8192][64] (2 MB)
#define WS_BIAS (8u << 20)                  // -||e_j||^2/2 (32 KB)
#define WS_PB1  (WS_BIAS + (64u << 10))     // 1 MB
#define WS_PI1  (WS_PB1 + (1u << 20))       // 1 MB
#define WS_PB2  (WS_PI1 + (1u << 20))       // 1 MB

__device__ __forceinline__ u32 f32_key(float s) {
    u32 u = __float_as_uint(s);
    return (u & 0x80000000u) ? ~u : (u | 0x80000000u);
}

__device__ __forceinline__ void async16(const void* g, void* l) {
    __builtin_amdgcn_global_load_lds(
        (const __attribute__((address_space(1))) void*)g,
        (__attribute__((address_space(3))) void*)l, 16, 0, 0);
}

// ---- K1: prep. Blocks 0..255: transpose x -> xT fp32 [row][64].
//          Blocks 256..383: embedT fp32, bias, swizzled bf16 code groups.
__global__ __launch_bounds__(256) void prep(
        const float* __restrict__ x, const float* __restrict__ embed, char* ws) {
    __shared__ float tile[64][65];
    float* xT   = (float*)(ws + WS_XT);
    float* eT   = (float*)(ws + WS_ET);
    float* bias = (float*)(ws + WS_BIAS);
    const int t = threadIdx.x;
    const int blk = blockIdx.x;

    if (blk < 256) {
        const int b = blk >> 4, p0 = (blk & 15) * 64;
        {
            const int c = t >> 2, seg = (t & 3) * 16;
            const float* src = x + b * 65536 + c * 1024 + p0 + seg;
#pragma unroll
            for (int i = 0; i < 16; ++i) tile[c][seg + i] = src[i];
        }
        __syncthreads();
        const int p = t >> 2, cq = (t & 3) * 16;
        const long row = (long)b * 1024 + p0 + p;
        float* dst = xT + row * 64 + cq;
#pragma unroll
        for (int i = 0; i < 16; i += 4) {
            f32x4 v = {tile[cq + i][p], tile[cq + i + 1][p],
                       tile[cq + i + 2][p], tile[cq + i + 3][p]};
            *(f32x4*)(dst + i) = v;
        }
    } else {
        const int g = blk - 256;             // 64-code group
        const int jbase = g * 64;
        char* Bg = ws + WS_B + (size_t)g * 16384;
        {
            const int c = t >> 2, seg = (t & 3) * 16;
            const float* src = embed + c * N_EMBED + jbase + seg;
#pragma unroll
            for (int i = 0; i < 16; ++i) tile[c][seg + i] = src[i];
        }
        __syncthreads();
        if (t < 64) {
            float s = 0.f;
#pragma unroll
            for (int c = 0; c < 64; ++c) { float v = tile[c][t]; s = fmaf(v, v, s); }
            bias[jbase + t] = -0.5f * s;
        }
        const int jl = t >> 2, cq = (t & 3) * 16;   // channels cq..cq+15
        bf16x8 vh0, vh1, vl0, vl1;
#pragma unroll
        for (int i = 0; i < 16; ++i) {
            float f = tile[cq + i][jl];
            eT[(long)(jbase + jl) * 64 + cq + i] = f;
            __bf16 h = (__bf16)f;
            __bf16 l = (__bf16)(f - (float)h);
            if (i < 8) { vh0[i] = h; vl0[i] = l; }
            else       { vh1[i - 8] = h; vl1[i - 8] = l; }
        }
        // granule-XOR swizzle: logical granule k (8 bf16) of code jl stored at
        // position k ^ (jl & 7). Staging stays contiguous; LDS reads conflict-free.
        const int k0 = (cq >> 3), sw = jl & 7;
        __bf16* hi = (__bf16*)Bg + jl * 64;
        __bf16* lo = (__bf16*)(Bg + 8192) + jl * 64;
        *(bf16x8*)(hi + ((k0 ^ sw) * 8))       = vh0;
        *(bf16x8*)(hi + (((k0 + 1) ^ sw) * 8)) = vh1;
        *(bf16x8*)(lo + ((k0 ^ sw) * 8))       = vl0;
        *(bf16x8*)(lo + (((k0 + 1) ^ sw) * 8)) = vl1;
    }
}

// ---- K2: MFMA GEMM + running (quad-max top-2) argmax. (R9 structure)
// grid 512 blocks (32 rowblk x 16 chunks), 256 thr, 2 blocks/CU.
__global__ __launch_bounds__(256, 2) void qdist(const char* __restrict__ ws_c, char* __restrict__ ws) {
    __shared__ __align__(16) char smem[2][16384];
    const float* xT = (const float*)(ws_c + WS_XT);
    const char* Bws = ws_c + WS_B;
    const float* biasg = (const float*)(ws_c + WS_BIAS);
    float* pb1 = (float*)(ws + WS_PB1);
    int*   pi1 = (int*)(ws + WS_PI1);
    float* pb2 = (float*)(ws + WS_PB2);

    const int t = threadIdx.x;
    const int wv = t >> 6, lane = t & 63, ln = lane & 15, q = lane >> 4;
    const int rb = blockIdx.x >> 4, chunk = blockIdx.x & 15;
    const int row0 = rb * ROWS_PER_BLOCK;
    const int col0 = chunk * COLS_PER_BLOCK;
    const int g0 = col0 >> 6;               // first 64-code group of this chunk

    // resident pixel fragments (B-operand): 8 pixel-tiles x 2 K-halves x {hi,lo},
    // split in-register from fp32 xT (one-time ~400 VALU).
    f32x4 pfh[8][2], pfl[8][2];
#pragma unroll
    for (int nt = 0; nt < 8; ++nt) {
        long row = row0 + wv * 128 + nt * 16 + ln;
        const float* xr = xT + row * 64 + q * 8;
        f32x4 f0 = *(const f32x4*)(xr);
        f32x4 f1 = *(const f32x4*)(xr + 4);
        f32x4 f2 = *(const f32x4*)(xr + 32);
        f32x4 f3 = *(const f32x4*)(xr + 36);
        split8(f0, f1, pfh[nt][0], pfl[nt][0]);
        split8(f2, f3, pfh[nt][1], pfl[nt][1]);
    }
    asm volatile("" :
        "+v"(pfh[0][0]), "+v"(pfh[0][1]), "+v"(pfh[1][0]), "+v"(pfh[1][1]),
        "+v"(pfh[2][0]), "+v"(pfh[2][1]), "+v"(pfh[3][0]), "+v"(pfh[3][1]),
        "+v"(pfh[4][0]), "+v"(pfh[4][1]), "+v"(pfh[5][0]), "+v"(pfh[5][1]),
        "+v"(pfh[6][0]), "+v"(pfh[6][1]), "+v"(pfh[7][0]), "+v"(pfh[7][1]));
    asm volatile("" :
        "+v"(pfl[0][0]), "+v"(pfl[0][1]), "+v"(pfl[1][0]), "+v"(pfl[1][1]),
        "+v"(pfl[2][0]), "+v"(pfl[2][1]), "+v"(pfl[3][0]), "+v"(pfl[3][1]),
        "+v"(pfl[4][0]), "+v"(pfl[4][1]), "+v"(pfl[5][0]), "+v"(pfl[5][1]),
        "+v"(pfl[6][0]), "+v"(pfl[6][1]), "+v"(pfl[7][0]), "+v"(pfl[7][1]));

    float b1[8], b2[8]; int iq[8];
#pragma unroll
    for (int k = 0; k < 8; ++k) { b1[k] = -3.4e38f; b2[k] = -3.4e38f; iq[k] = 0; }

    // swizzled fragment read offsets: code cl=ct*16+ln; hi-K0 granule q^(ln&7)
    const int s7 = ln & 7;
    const int rdbase = ln * 128 + ((q ^ s7) << 4);

    auto issue = [&](int st) {
        const char* src = Bws + (size_t)(g0 + st) * 16384;
        char* dst = smem[st & 1];
#pragma unroll
        for (int s = 0; s < 4; ++s)
            async16(src + s * 4096 + wv * 1024 + lane * 16,
                    dst + s * 4096 + wv * 1024);
    };

    issue(0);
    for (int st = 0; st < N_ST; ++st) {
        __syncthreads();                 // own staging drained (vmcnt0 before barrier);
        if (st + 1 < N_ST) issue(st + 1);// all waves done reading buf[(st+1)&1]
        const char* buf = smem[st & 1];
#pragma unroll
        for (int ct = 0; ct < 4; ++ct) {
            const int boff = ct * 2048 + rdbase;
            bf16x8 ah0 = *(const bf16x8*)(buf + boff);
            bf16x8 ah1 = *(const bf16x8*)(buf + (boff ^ 64));
            bf16x8 al0 = *(const bf16x8*)(buf + 8192 + boff);
            bf16x8 al1 = *(const bf16x8*)(buf + 8192 + (boff ^ 64));
            const int cbase = col0 + st * 64 + ct * 16;
            f32x4 bv = *(const f32x4*)(biasg + cbase + q * 4);  // bias for 4 codes
            const int jq = cbase + q * 4;
#pragma unroll
            for (int nt = 0; nt < 8; ++nt) {
                f32x4 acc = __builtin_amdgcn_mfma_f32_16x16x32_bf16(al0, as_bf16x8(pfh[nt][0]), bv, 0, 0, 0);
                acc = __builtin_amdgcn_mfma_f32_16x16x32_bf16(al1, as_bf16x8(pfh[nt][1]), acc, 0, 0, 0);
                acc = __builtin_amdgcn_mfma_f32_16x16x32_bf16(ah0, as_bf16x8(pfl[nt][0]), acc, 0, 0, 0);
                acc = __builtin_amdgcn_mfma_f32_16x16x32_bf16(ah1, as_bf16x8(pfl[nt][1]), acc, 0, 0, 0);
                acc = __builtin_amdgcn_mfma_f32_16x16x32_bf16(ah0, as_bf16x8(pfh[nt][0]), acc, 0, 0, 0);
                acc = __builtin_amdgcn_mfma_f32_16x16x32_bf16(ah1, as_bf16x8(pfh[nt][1]), acc, 0, 0, 0);
                // quad max (4 codes of one pixel)
                float mx = fmaxf(fmaxf(acc[0], acc[1]), fmaxf(acc[2], acc[3]));
                b2[nt] = fmaxf(b2[nt], fminf(b1[nt], mx));
                bool gt = mx > b1[nt];
                b1[nt] = fmaxf(b1[nt], mx);
                iq[nt] = gt ? jq : iq[nt];
            }
        }
    }

    // merge across the 4 quads (same pixel lives in lanes ln, ln+16, ln+32, ln+48)
#pragma unroll
    for (int m = 16; m < 64; m <<= 1) {
#pragma unroll
        for (int nt = 0; nt < 8; ++nt) {
            float o1 = __shfl_xor(b1[nt], m);
            int   oi = __shfl_xor(iq[nt], m);
            float o2 = __shfl_xor(b2[nt], m);
            b2[nt] = fmaxf(fmaxf(fminf(b1[nt], o1), o2), b2[nt]);
            bool take = (o1 > b1[nt]) || (o1 == b1[nt] && oi < iq[nt]);
            if (take) { b1[nt] = o1; iq[nt] = oi; }
        }
    }
    if (q == 0) {
#pragma unroll
        for (int nt = 0; nt < 8; ++nt) {
            int pixel = row0 + wv * 128 + nt * 16 + ln;
            int o = chunk * N_ROWS + pixel;
            pb1[o] = b1[nt];
            pi1[o] = iq[nt];
            pb2[o] = b2[nt];
        }
    }
}

// ---- K3: finish = chunk-merge + exact quad-pick + cooperative rescan of
//          near-ties + output gather. 64 blocks x 256 thr, 1 row/thread.
__global__ __launch_bounds__(256) void finish(char* __restrict__ ws,
                                              float* __restrict__ out) {
    __shared__ int   lfidx[256];     // final code idx per local row
    __shared__ int   flist[256];     // flagged local rows
    __shared__ int   nflag_s;
    __shared__ float xrow[64];
    __shared__ u64   red[256];
    const float* pb1 = (const float*)(ws + WS_PB1);
    const int*   pi1 = (const int*)(ws + WS_PI1);
    const float* pb2 = (const float*)(ws + WS_PB2);
    const float* eT  = (const float*)(ws + WS_ET);
    const float* bias = (const float*)(ws + WS_BIAS);
    const float* xT  = (const float*)(ws + WS_XT);
    const int t = threadIdx.x;
    const int row = blockIdx.x * 256 + t;

    if (t == 0) nflag_s = 0;
    __syncthreads();

    // merge the 16 chunk partials (coalesced: row = base + t)
    float b1 = pb1[row]; int iq = pi1[row]; float b2 = pb2[row];
#pragma unroll
    for (int ch = 1; ch < NCHUNK; ++ch) {
        float o1 = pb1[ch * N_ROWS + row];
        int   oi = pi1[ch * N_ROWS + row];
        float o2 = pb2[ch * N_ROWS + row];
        b2 = fmaxf(fmaxf(fminf(b1, o1), o2), b2);
        if (o1 > b1 || (o1 == b1 && oi < iq)) { b1 = o1; iq = oi; }
    }

    int myidx;
    if (b1 - b2 < MARGIN_THR) {
        flist[atomicAdd(&nflag_s, 1)] = t;
        myidx = 0;                       // overwritten by rescan
    } else {
        // exact fp32 argmax within the winning quad (codes iq..iq+3)
        float xr[64];
        const f32x4* xv = (const f32x4*)(xT + (size_t)row * 64);
#pragma unroll
        for (int v = 0; v < 16; ++v) { f32x4 w = xv[v];
#pragma unroll
            for (int k = 0; k < 4; ++k) xr[v * 4 + k] = w[k]; }
        float best = -3.4e38f; int bi = iq;
#pragma unroll
        for (int cc = 0; cc < 4; ++cc) {
            const int j = iq + cc;
            const float* e = eT + (size_t)j * 64;
            float s = bias[j];
#pragma unroll
            for (int c = 0; c < 64; ++c) s = fmaf(xr[c], e[c], s);
            if (s > best) { best = s; bi = j; }   // strict >, ascending j
        }
        myidx = bi;
    }
    lfidx[t] = myidx;
    __syncthreads();

    // cooperative exact rescan of flagged rows (expected ~0-2 per block)
    const int nf = nflag_s;
    for (int fi = 0; fi < nf; ++fi) {
        const int rt = flist[fi];
        const int grow = blockIdx.x * 256 + rt;
        __syncthreads();
        if (t < 16) ((f32x4*)xrow)[t] = ((const f32x4*)(xT + (size_t)grow * 64))[t];
        __syncthreads();
        float xr[64];
#pragma unroll
        for (int c = 0; c < 64; ++c) xr[c] = xrow[c];
        float lb = -3.4e38f; int li = 0;
        for (int k = 0; k < 32; ++k) {          // 32 codes per thread
            const int j = k * 256 + t;
            const f32x4* e = (const f32x4*)(eT + (size_t)j * 64);
            f32x4 a0 = {0.f, 0.f, 0.f, 0.f}, a1 = a0, a2 = a0, a3 = a0;
#pragma unroll
            for (int v = 0; v < 4; ++v) {
                f32x4 e0 = e[v * 4 + 0], e1 = e[v * 4 + 1];
                f32x4 e2 = e[v * 4 + 2], e3 = e[v * 4 + 3];
#pragma unroll
                for (int kk = 0; kk < 4; ++kk) {
                    a0[kk] = fmaf(xr[v * 16 + kk],      e0[kk], a0[kk]);
                    a1[kk] = fmaf(xr[v * 16 + 4 + kk],  e1[kk], a1[kk]);
                    a2[kk] = fmaf(xr[v * 16 + 8 + kk],  e2[kk], a2[kk]);
                    a3[kk] = fmaf(xr[v * 16 + 12 + kk], e3[kk], a3[kk]);
                }
            }
            f32x4 a01 = a0 + a1, a23 = a2 + a3;
            f32x4 as = a01 + a23;
            float s = bias[j] + ((as[0] + as[1]) + (as[2] + as[3]));
            if (s > lb) { lb = s; li = j; }
        }
        red[t] = ((u64)f32_key(lb) << 32) | (u32)(~(u32)li);
        __syncthreads();
        for (int off = 128; off; off >>= 1) {
            if (t < off) { u64 o = red[t + off]; if (o > red[t]) red[t] = o; }
            __syncthreads();
        }
        if (t == 0) lfidx[rt] = (int)(~(u32)red[0]);
    }
    __syncthreads();

    // gather: block covers out elements [base, base+16384)
    const size_t base = (size_t)blockIdx.x * 256 * 64;
#pragma unroll 4
    for (int i = 0; i < 64; ++i) {
        const int el = i * 256 + t;
        const int rl = el >> 6, c = el & 63;
        out[base + el] = eT[(size_t)lfidx[rl] * 64 + c];
    }
}

extern "C" void kernel_launch(void* const* d_in, const int* in_sizes, int n_in,
                              void* d_out, int out_size, void* d_ws, size_t ws_size,
                              hipStream_t stream) {
    const float* x     = (const float*)d_in[0];
    const float* embed = (const float*)d_in[1];
    float* out = (float*)d_out;
    char* ws = (char*)d_ws;

    prep<<<384, 256, 0, stream>>>(x, embed, ws);
    qdist<<<N_ROWBLK * NCHUNK, 256, 0, stream>>>(ws, ws);
    finish<<<N_ROWS / 256, 256, 0, stream>>>(ws, out);
}

// Round 13
// 250.639 us; speedup vs baseline: 1.1907x; 1.0484x over previous
//
#include <hip/hip_runtime.h>

// Quantizer via bf16x3-split MFMA GEMM + exact-fp32 recheck of near-ties.
//   x: [16,64,32,32] fp32, embed: [64,8192] fp32
//   out[row][c] = embedT[argmax_j (f_row.e_j - ||e_j||^2/2)][c]
//
// R13: finish parallelized 32x (512 blocks, 8 threads/row, candidate dots in
// parallel + shfl merge). R12's finish ran 64 blocks with serial per-thread
// quad-picks -> 0.85% occupancy, latency-bound 165 us (same failure mode as
// R8's recheck). prep/qdist unchanged.

typedef __attribute__((ext_vector_type(8))) __bf16 bf16x8;
typedef __attribute__((ext_vector_type(4))) float f32x4;
typedef unsigned int u32;
typedef unsigned long long u64;

union frag_cast { f32x4 f; bf16x8 b; };
__device__ __forceinline__ bf16x8 as_bf16x8(f32x4 v) { frag_cast u; u.f = v; return u.b; }

__device__ __forceinline__ void split8(f32x4 a, f32x4 b, f32x4& ho, f32x4& lo_) {
    frag_cast h, l;
#pragma unroll
    for (int i = 0; i < 4; ++i) {
        __bf16 ha = (__bf16)a[i];
        __bf16 hb = (__bf16)b[i];
        h.b[i]     = ha;
        h.b[i + 4] = hb;
        l.b[i]     = (__bf16)(a[i] - (float)ha);
        l.b[i + 4] = (__bf16)(b[i] - (float)hb);
    }
    ho = h.f; lo_ = l.f;
}

#define N_ROWS  16384
#define E_DIM   64
#define N_EMBED 8192
#define NCHUNK  16
#define COLS_PER_BLOCK (N_EMBED / NCHUNK)   // 512
#define N_ST (COLS_PER_BLOCK / 64)          // 8 stages of 64 codes
#define ROWS_PER_BLOCK 512                  // 4 waves x 128 pixels
#define N_ROWBLK (N_ROWS / ROWS_PER_BLOCK)  // 32
#define MARGIN_THR 2e-3f

// ---- workspace byte offsets (~11.1 MB total)
#define WS_XT   0u                          // pixels fp32 [16384][64] (4 MB)
#define WS_B    (4u << 20)                  // codes: 128 groups x [hi 8KB | lo 8KB] (2 MB)
#define WS_ET   (6u << 20)                  // embedT fp32 [8192][64] (2 MB)
#define WS_BIAS (8u << 20)                  // -||e_j||^2/2 (32 KB)
#define WS_PB1  (WS_BIAS + (64u << 10))     // 1 MB
#define WS_PI1  (WS_PB1 + (1u << 20))       // 1 MB
#define WS_PB2  (WS_PI1 + (1u << 20))       // 1 MB

__device__ __forceinline__ u32 f32_key(float s) {
    u32 u = __float_as_uint(s);
    return (u & 0x80000000u) ? ~u : (u | 0x80000000u);
}

__device__ __forceinline__ void async16(const void* g, void* l) {
    __builtin_amdgcn_global_load_lds(
        (const __attribute__((address_space(1))) void*)g,
        (__attribute__((address_space(3))) void*)l, 16, 0, 0);
}

// ---- K1: prep. Blocks 0..255: transpose x -> xT fp32 [row][64].
//          Blocks 256..383: embedT fp32, bias, swizzled bf16 code groups.
__global__ __launch_bounds__(256) void prep(
        const float* __restrict__ x, const float* __restrict__ embed, char* ws) {
    __shared__ float tile[64][65];
    float* xT   = (float*)(ws + WS_XT);
    float* eT   = (float*)(ws + WS_ET);
    float* bias = (float*)(ws + WS_BIAS);
    const int t = threadIdx.x;
    const int blk = blockIdx.x;

    if (blk < 256) {
        const int b = blk >> 4, p0 = (blk & 15) * 64;
        {
            const int c = t >> 2, seg = (t & 3) * 16;
            const float* src = x + b * 65536 + c * 1024 + p0 + seg;
#pragma unroll
            for (int i = 0; i < 16; ++i) tile[c][seg + i] = src[i];
        }
        __syncthreads();
        const int p = t >> 2, cq = (t & 3) * 16;
        const long row = (long)b * 1024 + p0 + p;
        float* dst = xT + row * 64 + cq;
#pragma unroll
        for (int i = 0; i < 16; i += 4) {
            f32x4 v = {tile[cq + i][p], tile[cq + i + 1][p],
                       tile[cq + i + 2][p], tile[cq + i + 3][p]};
            *(f32x4*)(dst + i) = v;
        }
    } else {
        const int g = blk - 256;             // 64-code group
        const int jbase = g * 64;
        char* Bg = ws + WS_B + (size_t)g * 16384;
        {
            const int c = t >> 2, seg = (t & 3) * 16;
            const float* src = embed + c * N_EMBED + jbase + seg;
#pragma unroll
            for (int i = 0; i < 16; ++i) tile[c][seg + i] = src[i];
        }
        __syncthreads();
        if (t < 64) {
            float s = 0.f;
#pragma unroll
            for (int c = 0; c < 64; ++c) { float v = tile[c][t]; s = fmaf(v, v, s); }
            bias[jbase + t] = -0.5f * s;
        }
        const int jl = t >> 2, cq = (t & 3) * 16;   // channels cq..cq+15
        bf16x8 vh0, vh1, vl0, vl1;
#pragma unroll
        for (int i = 0; i < 16; ++i) {
            float f = tile[cq + i][jl];
            eT[(long)(jbase + jl) * 64 + cq + i] = f;
            __bf16 h = (__bf16)f;
            __bf16 l = (__bf16)(f - (float)h);
            if (i < 8) { vh0[i] = h; vl0[i] = l; }
            else       { vh1[i - 8] = h; vl1[i - 8] = l; }
        }
        // granule-XOR swizzle: staging contiguous, LDS reads conflict-free
        const int k0 = (cq >> 3), sw = jl & 7;
        __bf16* hi = (__bf16*)Bg + jl * 64;
        __bf16* lo = (__bf16*)(Bg + 8192) + jl * 64;
        *(bf16x8*)(hi + ((k0 ^ sw) * 8))       = vh0;
        *(bf16x8*)(hi + (((k0 + 1) ^ sw) * 8)) = vh1;
        *(bf16x8*)(lo + ((k0 ^ sw) * 8))       = vl0;
        *(bf16x8*)(lo + (((k0 + 1) ^ sw) * 8)) = vl1;
    }
}

// ---- K2: MFMA GEMM + running (quad-max top-2) argmax. (proven ~50us config)
// grid 512 blocks (32 rowblk x 16 chunks), 256 thr, 2 blocks/CU.
__global__ __launch_bounds__(256, 2) void qdist(const char* __restrict__ ws_c, char* __restrict__ ws) {
    __shared__ __align__(16) char smem[2][16384];
    const float* xT = (const float*)(ws_c + WS_XT);
    const char* Bws = ws_c + WS_B;
    const float* biasg = (const float*)(ws_c + WS_BIAS);
    float* pb1 = (float*)(ws + WS_PB1);
    int*   pi1 = (int*)(ws + WS_PI1);
    float* pb2 = (float*)(ws + WS_PB2);

    const int t = threadIdx.x;
    const int wv = t >> 6, lane = t & 63, ln = lane & 15, q = lane >> 4;
    const int rb = blockIdx.x >> 4, chunk = blockIdx.x & 15;
    const int row0 = rb * ROWS_PER_BLOCK;
    const int col0 = chunk * COLS_PER_BLOCK;
    const int g0 = col0 >> 6;               // first 64-code group of this chunk

    // resident pixel fragments (B-operand), split in-register from fp32 xT
    f32x4 pfh[8][2], pfl[8][2];
#pragma unroll
    for (int nt = 0; nt < 8; ++nt) {
        long row = row0 + wv * 128 + nt * 16 + ln;
        const float* xr = xT + row * 64 + q * 8;
        f32x4 f0 = *(const f32x4*)(xr);
        f32x4 f1 = *(const f32x4*)(xr + 4);
        f32x4 f2 = *(const f32x4*)(xr + 32);
        f32x4 f3 = *(const f32x4*)(xr + 36);
        split8(f0, f1, pfh[nt][0], pfl[nt][0]);
        split8(f2, f3, pfh[nt][1], pfl[nt][1]);
    }
    asm volatile("" :
        "+v"(pfh[0][0]), "+v"(pfh[0][1]), "+v"(pfh[1][0]), "+v"(pfh[1][1]),
        "+v"(pfh[2][0]), "+v"(pfh[2][1]), "+v"(pfh[3][0]), "+v"(pfh[3][1]),
        "+v"(pfh[4][0]), "+v"(pfh[4][1]), "+v"(pfh[5][0]), "+v"(pfh[5][1]),
        "+v"(pfh[6][0]), "+v"(pfh[6][1]), "+v"(pfh[7][0]), "+v"(pfh[7][1]));
    asm volatile("" :
        "+v"(pfl[0][0]), "+v"(pfl[0][1]), "+v"(pfl[1][0]), "+v"(pfl[1][1]),
        "+v"(pfl[2][0]), "+v"(pfl[2][1]), "+v"(pfl[3][0]), "+v"(pfl[3][1]),
        "+v"(pfl[4][0]), "+v"(pfl[4][1]), "+v"(pfl[5][0]), "+v"(pfl[5][1]),
        "+v"(pfl[6][0]), "+v"(pfl[6][1]), "+v"(pfl[7][0]), "+v"(pfl[7][1]));

    float b1[8], b2[8]; int iq[8];
#pragma unroll
    for (int k = 0; k < 8; ++k) { b1[k] = -3.4e38f; b2[k] = -3.4e38f; iq[k] = 0; }

    const int s7 = ln & 7;
    const int rdbase = ln * 128 + ((q ^ s7) << 4);

    auto issue = [&](int st) {
        const char* src = Bws + (size_t)(g0 + st) * 16384;
        char* dst = smem[st & 1];
#pragma unroll
        for (int s = 0; s < 4; ++s)
            async16(src + s * 4096 + wv * 1024 + lane * 16,
                    dst + s * 4096 + wv * 1024);
    };

    issue(0);
    for (int st = 0; st < N_ST; ++st) {
        __syncthreads();
        if (st + 1 < N_ST) issue(st + 1);
        const char* buf = smem[st & 1];
#pragma unroll
        for (int ct = 0; ct < 4; ++ct) {
            const int boff = ct * 2048 + rdbase;
            bf16x8 ah0 = *(const bf16x8*)(buf + boff);
            bf16x8 ah1 = *(const bf16x8*)(buf + (boff ^ 64));
            bf16x8 al0 = *(const bf16x8*)(buf + 8192 + boff);
            bf16x8 al1 = *(const bf16x8*)(buf + 8192 + (boff ^ 64));
            const int cbase = col0 + st * 64 + ct * 16;
            f32x4 bv = *(const f32x4*)(biasg + cbase + q * 4);
            const int jq = cbase + q * 4;
#pragma unroll
            for (int nt = 0; nt < 8; ++nt) {
                f32x4 acc = __builtin_amdgcn_mfma_f32_16x16x32_bf16(al0, as_bf16x8(pfh[nt][0]), bv, 0, 0, 0);
                acc = __builtin_amdgcn_mfma_f32_16x16x32_bf16(al1, as_bf16x8(pfh[nt][1]), acc, 0, 0, 0);
                acc = __builtin_amdgcn_mfma_f32_16x16x32_bf16(ah0, as_bf16x8(pfl[nt][0]), acc, 0, 0, 0);
                acc = __builtin_amdgcn_mfma_f32_16x16x32_bf16(ah1, as_bf16x8(pfl[nt][1]), acc, 0, 0, 0);
                acc = __builtin_amdgcn_mfma_f32_16x16x32_bf16(ah0, as_bf16x8(pfh[nt][0]), acc, 0, 0, 0);
                acc = __builtin_amdgcn_mfma_f32_16x16x32_bf16(ah1, as_bf16x8(pfh[nt][1]), acc, 0, 0, 0);
                float mx = fmaxf(fmaxf(acc[0], acc[1]), fmaxf(acc[2], acc[3]));
                b2[nt] = fmaxf(b2[nt], fminf(b1[nt], mx));
                bool gt = mx > b1[nt];
                b1[nt] = fmaxf(b1[nt], mx);
                iq[nt] = gt ? jq : iq[nt];
            }
        }
    }

#pragma unroll
    for (int m = 16; m < 64; m <<= 1) {
#pragma unroll
        for (int nt = 0; nt < 8; ++nt) {
            float o1 = __shfl_xor(b1[nt], m);
            int   oi = __shfl_xor(iq[nt], m);
            float o2 = __shfl_xor(b2[nt], m);
            b2[nt] = fmaxf(fmaxf(fminf(b1[nt], o1), o2), b2[nt]);
            bool take = (o1 > b1[nt]) || (o1 == b1[nt] && oi < iq[nt]);
            if (take) { b1[nt] = o1; iq[nt] = oi; }
        }
    }
    if (q == 0) {
#pragma unroll
        for (int nt = 0; nt < 8; ++nt) {
            int pixel = row0 + wv * 128 + nt * 16 + ln;
            int o = chunk * N_ROWS + pixel;
            pb1[o] = b1[nt];
            pi1[o] = iq[nt];
            pb2[o] = b2[nt];
        }
    }
}

// ---- K3: finish = chunk-merge + parallel exact quad-pick (4 thr/row) +
//          cooperative rescan of near-ties + gather. 512 blocks, 32 rows each.
__global__ __launch_bounds__(256) void finish(char* __restrict__ ws,
                                              float* __restrict__ out) {
    __shared__ int   lfidx[32];      // final code idx per local row
    __shared__ int   flist[32];      // flagged local rows
    __shared__ int   nflag_s;
    __shared__ float xrow[64];
    __shared__ u64   red[256];
    const float* pb1 = (const float*)(ws + WS_PB1);
    const int*   pi1 = (const int*)(ws + WS_PI1);
    const float* pb2 = (const float*)(ws + WS_PB2);
    const float* eT  = (const float*)(ws + WS_ET);
    const float* bias = (const float*)(ws + WS_BIAS);
    const float* xT  = (const float*)(ws + WS_XT);
    const int t = threadIdx.x;
    const int r = t >> 3, sub = t & 7;          // 8 threads per row
    const int row = blockIdx.x * 32 + r;

    if (t == 0) nflag_s = 0;
    __syncthreads();

    // merge the 16 chunk partials (redundant x8; broadcast loads)
    float b1 = pb1[row]; int iq = pi1[row]; float b2 = pb2[row];
#pragma unroll
    for (int ch = 1; ch < NCHUNK; ++ch) {
        float o1 = pb1[ch * N_ROWS + row];
        int   oi = pi1[ch * N_ROWS + row];
        float o2 = pb2[ch * N_ROWS + row];
        b2 = fmaxf(fmaxf(fminf(b1, o1), o2), b2);
        if (o1 > b1 || (o1 == b1 && oi < iq)) { b1 = o1; iq = oi; }
    }

    const bool flagged = (b1 - b2 < MARGIN_THR);
    if (sub == 0 && flagged) flist[atomicAdd(&nflag_s, 1)] = r;

    // parallel exact quad-pick: subs 0..3 each compute one candidate dot
    u64 key = 0;
    if (sub < 4) {
        const int j = iq + sub;
        const f32x4* xv = (const f32x4*)(xT + (size_t)row * 64);
        const f32x4* ev = (const f32x4*)(eT + (size_t)j * 64);
        f32x4 a0 = {0.f, 0.f, 0.f, 0.f}, a1 = a0, a2 = a0, a3 = a0;
#pragma unroll
        for (int v = 0; v < 4; ++v) {
            f32x4 x0 = xv[v * 4 + 0], x1 = xv[v * 4 + 1];
            f32x4 x2 = xv[v * 4 + 2], x3 = xv[v * 4 + 3];
            f32x4 e0 = ev[v * 4 + 0], e1 = ev[v * 4 + 1];
            f32x4 e2 = ev[v * 4 + 2], e3 = ev[v * 4 + 3];
#pragma unroll
            for (int k = 0; k < 4; ++k) {
                a0[k] = fmaf(x0[k], e0[k], a0[k]);
                a1[k] = fmaf(x1[k], e1[k], a1[k]);
                a2[k] = fmaf(x2[k], e2[k], a2[k]);
                a3[k] = fmaf(x3[k], e3[k], a3[k]);
            }
        }
        f32x4 a01 = a0 + a1, a23 = a2 + a3;
        f32x4 as = a01 + a23;
        float s = bias[j] + ((as[0] + as[1]) + (as[2] + as[3]));
        key = ((u64)f32_key(s) << 32) | (u32)(~(u32)j);   // tie -> smaller j
    }
    { u64 o = __shfl_xor(key, 1); if (o > key) key = o; }
    { u64 o = __shfl_xor(key, 2); if (o > key) key = o; }
    if (sub == 0) lfidx[r] = (int)(~(u32)key);
    __syncthreads();

    // cooperative exact rescan of flagged rows (expected ~0-1 per block)
    const int nf = nflag_s;
    for (int fi = 0; fi < nf; ++fi) {
        const int rt = flist[fi];
        const int grow = blockIdx.x * 32 + rt;
        __syncthreads();
        if (t < 16) ((f32x4*)xrow)[t] = ((const f32x4*)(xT + (size_t)grow * 64))[t];
        __syncthreads();
        float xr[64];
#pragma unroll
        for (int c = 0; c < 64; ++c) xr[c] = xrow[c];
        float lb = -3.4e38f; int li = 0;
        for (int k = 0; k < 32; ++k) {          // 32 codes per thread
            const int j = k * 256 + t;
            const f32x4* e = (const f32x4*)(eT + (size_t)j * 64);
            f32x4 a0 = {0.f, 0.f, 0.f, 0.f}, a1 = a0, a2 = a0, a3 = a0;
#pragma unroll
            for (int v = 0; v < 4; ++v) {
                f32x4 e0 = e[v * 4 + 0], e1 = e[v * 4 + 1];
                f32x4 e2 = e[v * 4 + 2], e3 = e[v * 4 + 3];
#pragma unroll
                for (int kk = 0; kk < 4; ++kk) {
                    a0[kk] = fmaf(xr[v * 16 + kk],      e0[kk], a0[kk]);
                    a1[kk] = fmaf(xr[v * 16 + 4 + kk],  e1[kk], a1[kk]);
                    a2[kk] = fmaf(xr[v * 16 + 8 + kk],  e2[kk], a2[kk]);
                    a3[kk] = fmaf(xr[v * 16 + 12 + kk], e3[kk], a3[kk]);
                }
            }
            f32x4 a01 = a0 + a1, a23 = a2 + a3;
            f32x4 as = a01 + a23;
            float s = bias[j] + ((as[0] + as[1]) + (as[2] + as[3]));
            if (s > lb) { lb = s; li = j; }
        }
        red[t] = ((u64)f32_key(lb) << 32) | (u32)(~(u32)li);
        __syncthreads();
        for (int off = 128; off; off >>= 1) {
            if (t < off) { u64 o = red[t + off]; if (o > red[t]) red[t] = o; }
            __syncthreads();
        }
        if (t == 0) lfidx[rt] = (int)(~(u32)red[0]);
    }
    __syncthreads();

    // gather: block covers out elements [base, base+2048)
    const size_t base = (size_t)blockIdx.x * 32 * 64;
#pragma unroll
    for (int i = 0; i < 8; ++i) {
        const int el = i * 256 + t;
        const int rl = el >> 6, c = el & 63;
        out[base + el] = eT[(size_t)lfidx[rl] * 64 + c];
    }
}

extern "C" void kernel_launch(void* const* d_in, const int* in_sizes, int n_in,
                              void* d_out, int out_size, void* d_ws, size_t ws_size,
                              hipStream_t stream) {
    const float* x     = (const float*)d_in[0];
    const float* embed = (const float*)d_in[1];
    float* out = (float*)d_out;
    char* ws = (char*)d_ws;

    prep<<<384, 256, 0, stream>>>(x, embed, ws);
    qdist<<<N_ROWBLK * NCHUNK, 256, 0, stream>>>(ws, ws);
    finish<<<N_ROWS / 32, 256, 0, stream>>>(ws, out);
}

// Round 14
// 236.950 us; speedup vs baseline: 1.2595x; 1.0578x over previous
//
#include <hip/hip_runtime.h>

// Quantizer via bf16x3-split MFMA GEMM + exact-fp32 recheck of near-ties.
//   x: [16,64,32,32] fp32, embed: [64,8192] fp32
//   out[row][c] = embedT[argmax_j (f_row.e_j - ||e_j||^2/2)][c]
//
// R14: finish de-spilled. R13's rescan held a float xr[64] per-thread array
// under VGPR_Count=68 -> scratch spill -> straggler blocks ran ~140us
// (Occupancy 2%). Rescan now reads the pixel vector straight from LDS
// (broadcast ds_read) and uses 2 accumulators; quad-pick likewise.
// prep/qdist unchanged (proven ~50us qdist).

typedef __attribute__((ext_vector_type(8))) __bf16 bf16x8;
typedef __attribute__((ext_vector_type(4))) float f32x4;
typedef unsigned int u32;
typedef unsigned long long u64;

union frag_cast { f32x4 f; bf16x8 b; };
__device__ __forceinline__ bf16x8 as_bf16x8(f32x4 v) { frag_cast u; u.f = v; return u.b; }

__device__ __forceinline__ void split8(f32x4 a, f32x4 b, f32x4& ho, f32x4& lo_) {
    frag_cast h, l;
#pragma unroll
    for (int i = 0; i < 4; ++i) {
        __bf16 ha = (__bf16)a[i];
        __bf16 hb = (__bf16)b[i];
        h.b[i]     = ha;
        h.b[i + 4] = hb;
        l.b[i]     = (__bf16)(a[i] - (float)ha);
        l.b[i + 4] = (__bf16)(b[i] - (float)hb);
    }
    ho = h.f; lo_ = l.f;
}

#define N_ROWS  16384
#define E_DIM   64
#define N_EMBED 8192
#define NCHUNK  16
#define COLS_PER_BLOCK (N_EMBED / NCHUNK)   // 512
#define N_ST (COLS_PER_BLOCK / 64)          // 8 stages of 64 codes
#define ROWS_PER_BLOCK 512                  // 4 waves x 128 pixels
#define N_ROWBLK (N_ROWS / ROWS_PER_BLOCK)  // 32
#define MARGIN_THR 2e-3f

// ---- workspace byte offsets (~11.1 MB total)
#define WS_XT   0u                          // pixels fp32 [16384][64] (4 MB)
#define WS_B    (4u << 20)                  // codes: 128 groups x [hi 8KB | lo 8KB] (2 MB)
#define WS_ET   (6u << 20)                  // embedT fp32 [8192][64] (2 MB)
#define WS_BIAS (8u << 20)                  // -||e_j||^2/2 (32 KB)
#define WS_PB1  (WS_BIAS + (64u << 10))     // 1 MB
#define WS_PI1  (WS_PB1 + (1u << 20))       // 1 MB
#define WS_PB2  (WS_PI1 + (1u << 20))       // 1 MB

__device__ __forceinline__ u32 f32_key(float s) {
    u32 u = __float_as_uint(s);
    return (u & 0x80000000u) ? ~u : (u | 0x80000000u);
}

__device__ __forceinline__ void async16(const void* g, void* l) {
    __builtin_amdgcn_global_load_lds(
        (const __attribute__((address_space(1))) void*)g,
        (__attribute__((address_space(3))) void*)l, 16, 0, 0);
}

// ---- K1: prep. Blocks 0..255: transpose x -> xT fp32 [row][64].
//          Blocks 256..383: embedT fp32, bias, swizzled bf16 code groups.
__global__ __launch_bounds__(256) void prep(
        const float* __restrict__ x, const float* __restrict__ embed, char* ws) {
    __shared__ float tile[64][65];
    float* xT   = (float*)(ws + WS_XT);
    float* eT   = (float*)(ws + WS_ET);
    float* bias = (float*)(ws + WS_BIAS);
    const int t = threadIdx.x;
    const int blk = blockIdx.x;

    if (blk < 256) {
        const int b = blk >> 4, p0 = (blk & 15) * 64;
        {
            const int c = t >> 2, seg = (t & 3) * 16;
            const float* src = x + b * 65536 + c * 1024 + p0 + seg;
#pragma unroll
            for (int i = 0; i < 16; ++i) tile[c][seg + i] = src[i];
        }
        __syncthreads();
        const int p = t >> 2, cq = (t & 3) * 16;
        const long row = (long)b * 1024 + p0 + p;
        float* dst = xT + row * 64 + cq;
#pragma unroll
        for (int i = 0; i < 16; i += 4) {
            f32x4 v = {tile[cq + i][p], tile[cq + i + 1][p],
                       tile[cq + i + 2][p], tile[cq + i + 3][p]};
            *(f32x4*)(dst + i) = v;
        }
    } else {
        const int g = blk - 256;             // 64-code group
        const int jbase = g * 64;
        char* Bg = ws + WS_B + (size_t)g * 16384;
        {
            const int c = t >> 2, seg = (t & 3) * 16;
            const float* src = embed + c * N_EMBED + jbase + seg;
#pragma unroll
            for (int i = 0; i < 16; ++i) tile[c][seg + i] = src[i];
        }
        __syncthreads();
        if (t < 64) {
            float s = 0.f;
#pragma unroll
            for (int c = 0; c < 64; ++c) { float v = tile[c][t]; s = fmaf(v, v, s); }
            bias[jbase + t] = -0.5f * s;
        }
        const int jl = t >> 2, cq = (t & 3) * 16;   // channels cq..cq+15
        bf16x8 vh0, vh1, vl0, vl1;
#pragma unroll
        for (int i = 0; i < 16; ++i) {
            float f = tile[cq + i][jl];
            eT[(long)(jbase + jl) * 64 + cq + i] = f;
            __bf16 h = (__bf16)f;
            __bf16 l = (__bf16)(f - (float)h);
            if (i < 8) { vh0[i] = h; vl0[i] = l; }
            else       { vh1[i - 8] = h; vl1[i - 8] = l; }
        }
        // granule-XOR swizzle: staging contiguous, LDS reads conflict-free
        const int k0 = (cq >> 3), sw = jl & 7;
        __bf16* hi = (__bf16*)Bg + jl * 64;
        __bf16* lo = (__bf16*)(Bg + 8192) + jl * 64;
        *(bf16x8*)(hi + ((k0 ^ sw) * 8))       = vh0;
        *(bf16x8*)(hi + (((k0 + 1) ^ sw) * 8)) = vh1;
        *(bf16x8*)(lo + ((k0 ^ sw) * 8))       = vl0;
        *(bf16x8*)(lo + (((k0 + 1) ^ sw) * 8)) = vl1;
    }
}

// ---- K2: MFMA GEMM + running (quad-max top-2) argmax. (proven ~50us config)
// grid 512 blocks (32 rowblk x 16 chunks), 256 thr, 2 blocks/CU.
__global__ __launch_bounds__(256, 2) void qdist(const char* __restrict__ ws_c, char* __restrict__ ws) {
    __shared__ __align__(16) char smem[2][16384];
    const float* xT = (const float*)(ws_c + WS_XT);
    const char* Bws = ws_c + WS_B;
    const float* biasg = (const float*)(ws_c + WS_BIAS);
    float* pb1 = (float*)(ws + WS_PB1);
    int*   pi1 = (int*)(ws + WS_PI1);
    float* pb2 = (float*)(ws + WS_PB2);

    const int t = threadIdx.x;
    const int wv = t >> 6, lane = t & 63, ln = lane & 15, q = lane >> 4;
    const int rb = blockIdx.x >> 4, chunk = blockIdx.x & 15;
    const int row0 = rb * ROWS_PER_BLOCK;
    const int col0 = chunk * COLS_PER_BLOCK;
    const int g0 = col0 >> 6;               // first 64-code group of this chunk

    // resident pixel fragments (B-operand), split in-register from fp32 xT
    f32x4 pfh[8][2], pfl[8][2];
#pragma unroll
    for (int nt = 0; nt < 8; ++nt) {
        long row = row0 + wv * 128 + nt * 16 + ln;
        const float* xr = xT + row * 64 + q * 8;
        f32x4 f0 = *(const f32x4*)(xr);
        f32x4 f1 = *(const f32x4*)(xr + 4);
        f32x4 f2 = *(const f32x4*)(xr + 32);
        f32x4 f3 = *(const f32x4*)(xr + 36);
        split8(f0, f1, pfh[nt][0], pfl[nt][0]);
        split8(f2, f3, pfh[nt][1], pfl[nt][1]);
    }
    asm volatile("" :
        "+v"(pfh[0][0]), "+v"(pfh[0][1]), "+v"(pfh[1][0]), "+v"(pfh[1][1]),
        "+v"(pfh[2][0]), "+v"(pfh[2][1]), "+v"(pfh[3][0]), "+v"(pfh[3][1]),
        "+v"(pfh[4][0]), "+v"(pfh[4][1]), "+v"(pfh[5][0]), "+v"(pfh[5][1]),
        "+v"(pfh[6][0]), "+v"(pfh[6][1]), "+v"(pfh[7][0]), "+v"(pfh[7][1]));
    asm volatile("" :
        "+v"(pfl[0][0]), "+v"(pfl[0][1]), "+v"(pfl[1][0]), "+v"(pfl[1][1]),
        "+v"(pfl[2][0]), "+v"(pfl[2][1]), "+v"(pfl[3][0]), "+v"(pfl[3][1]),
        "+v"(pfl[4][0]), "+v"(pfl[4][1]), "+v"(pfl[5][0]), "+v"(pfl[5][1]),
        "+v"(pfl[6][0]), "+v"(pfl[6][1]), "+v"(pfl[7][0]), "+v"(pfl[7][1]));

    float b1[8], b2[8]; int iq[8];
#pragma unroll
    for (int k = 0; k < 8; ++k) { b1[k] = -3.4e38f; b2[k] = -3.4e38f; iq[k] = 0; }

    const int s7 = ln & 7;
    const int rdbase = ln * 128 + ((q ^ s7) << 4);

    auto issue = [&](int st) {
        const char* src = Bws + (size_t)(g0 + st) * 16384;
        char* dst = smem[st & 1];
#pragma unroll
        for (int s = 0; s < 4; ++s)
            async16(src + s * 4096 + wv * 1024 + lane * 16,
                    dst + s * 4096 + wv * 1024);
    };

    issue(0);
    for (int st = 0; st < N_ST; ++st) {
        __syncthreads();
        if (st + 1 < N_ST) issue(st + 1);
        const char* buf = smem[st & 1];
#pragma unroll
        for (int ct = 0; ct < 4; ++ct) {
            const int boff = ct * 2048 + rdbase;
            bf16x8 ah0 = *(const bf16x8*)(buf + boff);
            bf16x8 ah1 = *(const bf16x8*)(buf + (boff ^ 64));
            bf16x8 al0 = *(const bf16x8*)(buf + 8192 + boff);
            bf16x8 al1 = *(const bf16x8*)(buf + 8192 + (boff ^ 64));
            const int cbase = col0 + st * 64 + ct * 16;
            f32x4 bv = *(const f32x4*)(biasg + cbase + q * 4);
            const int jq = cbase + q * 4;
#pragma unroll
            for (int nt = 0; nt < 8; ++nt) {
                f32x4 acc = __builtin_amdgcn_mfma_f32_16x16x32_bf16(al0, as_bf16x8(pfh[nt][0]), bv, 0, 0, 0);
                acc = __builtin_amdgcn_mfma_f32_16x16x32_bf16(al1, as_bf16x8(pfh[nt][1]), acc, 0, 0, 0);
                acc = __builtin_amdgcn_mfma_f32_16x16x32_bf16(ah0, as_bf16x8(pfl[nt][0]), acc, 0, 0, 0);
                acc = __builtin_amdgcn_mfma_f32_16x16x32_bf16(ah1, as_bf16x8(pfl[nt][1]), acc, 0, 0, 0);
                acc = __builtin_amdgcn_mfma_f32_16x16x32_bf16(ah0, as_bf16x8(pfh[nt][0]), acc, 0, 0, 0);
                acc = __builtin_amdgcn_mfma_f32_16x16x32_bf16(ah1, as_bf16x8(pfh[nt][1]), acc, 0, 0, 0);
                float mx = fmaxf(fmaxf(acc[0], acc[1]), fmaxf(acc[2], acc[3]));
                b2[nt] = fmaxf(b2[nt], fminf(b1[nt], mx));
                bool gt = mx > b1[nt];
                b1[nt] = fmaxf(b1[nt], mx);
                iq[nt] = gt ? jq : iq[nt];
            }
        }
    }

#pragma unroll
    for (int m = 16; m < 64; m <<= 1) {
#pragma unroll
        for (int nt = 0; nt < 8; ++nt) {
            float o1 = __shfl_xor(b1[nt], m);
            int   oi = __shfl_xor(iq[nt], m);
            float o2 = __shfl_xor(b2[nt], m);
            b2[nt] = fmaxf(fmaxf(fminf(b1[nt], o1), o2), b2[nt]);
            bool take = (o1 > b1[nt]) || (o1 == b1[nt] && oi < iq[nt]);
            if (take) { b1[nt] = o1; iq[nt] = oi; }
        }
    }
    if (q == 0) {
#pragma unroll
        for (int nt = 0; nt < 8; ++nt) {
            int pixel = row0 + wv * 128 + nt * 16 + ln;
            int o = chunk * N_ROWS + pixel;
            pb1[o] = b1[nt];
            pi1[o] = iq[nt];
            pb2[o] = b2[nt];
        }
    }
}

// ---- K3: finish = chunk-merge + parallel exact quad-pick (4 of 8 thr/row) +
//          cooperative rescan of near-ties (LDS-direct, no big arrays) + gather.
__global__ __launch_bounds__(256) void finish(const char* __restrict__ ws,
                                              float* __restrict__ out) {
    __shared__ int   lfidx[32];      // final code idx per local row
    __shared__ int   flist[32];      // flagged local rows
    __shared__ int   nflag_s;
    __shared__ float xrow[64];
    __shared__ u64   red[256];
    const float* pb1 = (const float*)(ws + WS_PB1);
    const int*   pi1 = (const int*)(ws + WS_PI1);
    const float* pb2 = (const float*)(ws + WS_PB2);
    const float* eT  = (const float*)(ws + WS_ET);
    const float* bias = (const float*)(ws + WS_BIAS);
    const float* xT  = (const float*)(ws + WS_XT);
    const int t = threadIdx.x;
    const int r = t >> 3, sub = t & 7;          // 8 threads per row
    const int row = blockIdx.x * 32 + r;

    if (t == 0) nflag_s = 0;
    __syncthreads();

    // merge the 16 chunk partials (redundant x8; broadcast loads)
    float b1 = pb1[row]; int iq = pi1[row]; float b2 = pb2[row];
#pragma unroll
    for (int ch = 1; ch < NCHUNK; ++ch) {
        float o1 = pb1[ch * N_ROWS + row];
        int   oi = pi1[ch * N_ROWS + row];
        float o2 = pb2[ch * N_ROWS + row];
        b2 = fmaxf(fmaxf(fminf(b1, o1), o2), b2);
        if (o1 > b1 || (o1 == b1 && oi < iq)) { b1 = o1; iq = oi; }
    }

    const bool flagged = (b1 - b2 < MARGIN_THR);
    if (sub == 0 && flagged) flist[atomicAdd(&nflag_s, 1)] = r;

    // parallel exact quad-pick: subs 0..3 each one candidate dot, 2 accumulators
    u64 key = 0;
    if (sub < 4) {
        const int j = iq + sub;
        const f32x4* xv = (const f32x4*)(xT + (size_t)row * 64);
        const f32x4* ev = (const f32x4*)(eT + (size_t)j * 64);
        f32x4 a0 = {0.f, 0.f, 0.f, 0.f}, a1 = a0;
#pragma unroll
        for (int v = 0; v < 8; ++v) {
            f32x4 x0 = xv[v * 2 + 0], x1 = xv[v * 2 + 1];
            f32x4 e0 = ev[v * 2 + 0], e1 = ev[v * 2 + 1];
#pragma unroll
            for (int k = 0; k < 4; ++k) {
                a0[k] = fmaf(x0[k], e0[k], a0[k]);
                a1[k] = fmaf(x1[k], e1[k], a1[k]);
            }
        }
        f32x4 as = a0 + a1;
        float s = bias[j] + ((as[0] + as[1]) + (as[2] + as[3]));
        key = ((u64)f32_key(s) << 32) | (u32)(~(u32)j);   // tie -> smaller j
    }
    { u64 o = __shfl_xor(key, 1); if (o > key) key = o; }
    { u64 o = __shfl_xor(key, 2); if (o > key) key = o; }
    if (sub == 0) lfidx[r] = (int)(~(u32)key);
    __syncthreads();

    // cooperative exact rescan of flagged rows: pixel vector stays in LDS
    // (broadcast ds_read per FMA -- no per-thread xr[64] array, no spill)
    const int nf = nflag_s;
    for (int fi = 0; fi < nf; ++fi) {
        const int rt = flist[fi];
        const int grow = blockIdx.x * 32 + rt;
        __syncthreads();
        if (t < 16) ((f32x4*)xrow)[t] = ((const f32x4*)(xT + (size_t)grow * 64))[t];
        __syncthreads();
        float lb = -3.4e38f; int li = 0;
        for (int k = 0; k < 32; ++k) {          // 32 codes per thread
            const int j = k * 256 + t;
            const f32x4* e = (const f32x4*)(eT + (size_t)j * 64);
            f32x4 a0 = {0.f, 0.f, 0.f, 0.f}, a1 = a0;
#pragma unroll
            for (int v = 0; v < 8; ++v) {
                f32x4 e0 = e[v * 2 + 0], e1 = e[v * 2 + 1];
#pragma unroll
                for (int kk = 0; kk < 4; ++kk) {
                    a0[kk] = fmaf(xrow[v * 8 + kk],     e0[kk], a0[kk]);
                    a1[kk] = fmaf(xrow[v * 8 + 4 + kk], e1[kk], a1[kk]);
                }
            }
            f32x4 as = a0 + a1;
            float s = bias[j] + ((as[0] + as[1]) + (as[2] + as[3]));
            if (s > lb) { lb = s; li = j; }
        }
        red[t] = ((u64)f32_key(lb) << 32) | (u32)(~(u32)li);
        __syncthreads();
        for (int off = 128; off; off >>= 1) {
            if (t < off) { u64 o = red[t + off]; if (o > red[t]) red[t] = o; }
            __syncthreads();
        }
        if (t == 0) lfidx[rt] = (int)(~(u32)red[0]);
    }
    __syncthreads();

    // gather: block covers out elements [base, base+2048)
    const size_t base = (size_t)blockIdx.x * 32 * 64;
#pragma unroll
    for (int i = 0; i < 8; ++i) {
        const int el = i * 256 + t;
        const int rl = el >> 6, c = el & 63;
        out[base + el] = eT[(size_t)lfidx[rl] * 64 + c];
    }
}

extern "C" void kernel_launch(void* const* d_in, const int* in_sizes, int n_in,
                              void* d_out, int out_size, void* d_ws, size_t ws_size,
                              hipStream_t stream) {
    const float* x     = (const float*)d_in[0];
    const float* embed = (const float*)d_in[1];
    float* out = (float*)d_out;
    char* ws = (char*)d_ws;

    prep<<<384, 256, 0, stream>>>(x, embed, ws);
    qdist<<<N_ROWBLK * NCHUNK, 256, 0, stream>>>(ws, ws);
    finish<<<N_ROWS / 32, 256, 0, stream>>>(ws, out);
}